// Round 10
// baseline (245.318 us; speedup 1.0000x reference)
//
#include <hip/hip_runtime.h>

// ---------------------------------------------------------------------------
// GAT edge-average layer, MI355X.
// Phase 0 : k_wconv — Wf -> split-bf16 W' tables packed in MFMA fragment order
// Phase 1 : k_transform — 64-node tile; x staged via LDS (split-bf16, XOR-
//           swizzled); MFMA bf16x3; U stored bf16, Vb f32+bias; fused f64 p/q.
// Phase 2 : CSR build — XCD-WINDOWED histogram + scatter (atomics stay inside
//           one XCD's L2 -> no cross-XCD line churn), 2-level scan between.
// Phase 3 : k_node — 32 lanes/node, 8-edge-deep gather pipeline (shfl-
//           broadcast indices), f32 num / dual-chain f64 den, no atomics.
// ---------------------------------------------------------------------------

typedef short bf16x8 __attribute__((ext_vector_type(8)));
typedef short bf16x4 __attribute__((ext_vector_type(4)));
typedef float f32x4  __attribute__((ext_vector_type(4)));

__device__ inline short f32_to_bf16_rne(float f) {
    unsigned u = __float_as_uint(f);
    unsigned r = u + 0x7fffu + ((u >> 16) & 1u);
    return (short)(r >> 16);
}
__device__ inline float bf16s_to_f32(short s) {
    return __uint_as_float(((unsigned)(unsigned short)s) << 16);
}

// W'[c][k]: c<128 -> Wf[c][k] ; c>=128 -> Wf[c-128][128+k]
// Packed: whp[((ct*4+kt)*64+lane)*8 + j] = W'[ct*16+(lane&15)][kt*32+(lane>>4)*8+j]
__global__ __launch_bounds__(256) void k_wconv(
    const float* __restrict__ Wf, short* __restrict__ whp, short* __restrict__ wlp)
{
    int tid = blockIdx.x * 256 + threadIdx.x;     // 0..4095
    if (tid >= 4096) return;
    int ct = tid >> 8, kt = (tid >> 6) & 3, lane = tid & 63;
    int c = ct * 16 + (lane & 15);
    int kbase = kt * 32 + (lane >> 4) * 8;
    bf16x8 h, l;
    #pragma unroll
    for (int j = 0; j < 8; ++j) {
        int k = kbase + j;
        float v = (c < 128) ? Wf[c * 256 + k] : Wf[(c - 128) * 256 + 128 + k];
        short hs = f32_to_bf16_rne(v);
        h[j] = hs;
        l[j] = f32_to_bf16_rne(v - bf16s_to_f32(hs));
    }
    *(bf16x8*)(whp + (size_t)tid * 8) = h;
    *(bf16x8*)(wlp + (size_t)tid * 8) = l;
}

__global__ __launch_bounds__(256) void k_transform(
    const float* __restrict__ x, const short* __restrict__ whp,
    const short* __restrict__ wlp, const float* __restrict__ bf,
    const float* __restrict__ Ww, const float* __restrict__ bw,
    short* __restrict__ Ub, float* __restrict__ Vb,
    double* __restrict__ p, double* __restrict__ q, int N)
{
    __shared__ __attribute__((aligned(16))) char smem[32768];
    const int t = threadIdx.x, wv = t >> 6, lane = t & 63;
    const int n0 = blockIdx.x * 64;

    // ---- stage x -> split-bf16 LDS, XOR-swizzled (coalesced 1KB/instr) ----
    #pragma unroll
    for (int r = 0; r < 8; ++r) {
        int idx = r * 1024 + t * 4;              // f32 index in 64x128 tile
        int row = idx >> 7, col = idx & 127;
        int n = n0 + row;
        const float* sp = x + (size_t)((n < N) ? n : (N - 1)) * 128 + col;
        f32x4 v = *(const f32x4*)sp;
        bf16x4 hh, ll;
        #pragma unroll
        for (int j = 0; j < 4; ++j) {
            short hs = f32_to_bf16_rne(v[j]);
            hh[j] = hs;
            ll[j] = f32_to_bf16_rne(v[j] - bf16s_to_f32(hs));
        }
        int ba = (row * 256 + col * 2) ^ ((row & 7) << 4);
        *(bf16x4*)(smem + ba)         = hh;      // xh half
        *(bf16x4*)(smem + 16384 + ba) = ll;      // xl half
    }

    // ---- fused exact-f64 p/q: 4 lanes per node row, x rows are L2-warm ----
    {
        int row = wv * 16 + (lane >> 2);         // 0..63
        int n = n0 + row;
        int c0 = (lane & 3) * 32;
        const float* xr = x + (size_t)((n < N) ? n : (N - 1)) * 128 + c0;
        double ps = 0.0, qs = 0.0;
        #pragma unroll
        for (int jj = 0; jj < 32; jj += 4) {
            f32x4 v = *(const f32x4*)(xr + jj);
            #pragma unroll
            for (int j = 0; j < 4; ++j) {
                ps += (double)v[j] * (double)Ww[c0 + jj + j];
                qs += (double)v[j] * (double)Ww[128 + c0 + jj + j];
            }
        }
        ps += __shfl_xor(ps, 1); ps += __shfl_xor(ps, 2);
        qs += __shfl_xor(qs, 1); qs += __shfl_xor(qs, 2);
        if ((lane & 3) == 0 && n < N) {
            p[n] = ps;
            q[n] = qs + (double)bw[0];
        }
    }
    __syncthreads();

    // ---- compute: wave wv owns ct = wv*4 .. wv*4+3 ----
    f32x4 acc[4][4] = {};                        // [tt][nsub]
    #pragma unroll
    for (int tt = 0; tt < 4; ++tt) {
        const int ct = wv * 4 + tt;
        bf16x8 Wh[4], Wl[4];
        #pragma unroll
        for (int kt = 0; kt < 4; ++kt) {
            size_t off = (size_t)((ct * 4 + kt) * 64 + lane) * 8;
            Wh[kt] = *(const bf16x8*)(whp + off);    // 1KB contiguous per instr
            Wl[kt] = *(const bf16x8*)(wlp + off);
        }
        #pragma unroll
        for (int kt = 0; kt < 4; ++kt) {
            #pragma unroll
            for (int ns = 0; ns < 4; ++ns) {     // 4 independent dep-chains
                int row = ns * 16 + (lane & 15);
                int ba = (row * 256 + kt * 64 + (lane >> 4) * 16) ^ ((row & 7) << 4);
                bf16x8 xhf = *(const bf16x8*)(smem + ba);
                bf16x8 xlf = *(const bf16x8*)(smem + 16384 + ba);
                acc[tt][ns] = __builtin_amdgcn_mfma_f32_16x16x32_bf16(Wh[kt], xhf, acc[tt][ns], 0, 0, 0);
                acc[tt][ns] = __builtin_amdgcn_mfma_f32_16x16x32_bf16(Wh[kt], xlf, acc[tt][ns], 0, 0, 0);
                acc[tt][ns] = __builtin_amdgcn_mfma_f32_16x16x32_bf16(Wl[kt], xhf, acc[tt][ns], 0, 0, 0);
            }
        }
    }
    __syncthreads();

    // ---- epilogue pass 1: U (ct 0..7 = waves 0,1) via LDS, store bf16 ----
    if (wv < 2) {
        #pragma unroll
        for (int tt = 0; tt < 4; ++tt) {
            int cb = (wv * 4 + tt) * 64 + (lane >> 4) * 16;  // byte col offset
            #pragma unroll
            for (int ns = 0; ns < 4; ++ns) {
                int node = ns * 16 + (lane & 15);
                int ba = (node * 512 + cb) ^ ((node & 7) << 4);
                *(f32x4*)(smem + ba) = acc[tt][ns];
            }
        }
    }
    __syncthreads();
    #pragma unroll
    for (int r = 0; r < 8; ++r) {
        int fo = r * 4096 + t * 16;              // byte offset in [64][512]
        int row = fo >> 9;
        int col = (fo & 511) >> 2;
        if (n0 + row < N) {
            f32x4 v = *(const f32x4*)(smem + (fo ^ ((row & 7) << 4)));
            bf16x4 b;
            b[0] = f32_to_bf16_rne(v[0]); b[1] = f32_to_bf16_rne(v[1]);
            b[2] = f32_to_bf16_rne(v[2]); b[3] = f32_to_bf16_rne(v[3]);
            *(bf16x4*)(Ub + (size_t)(n0 + row) * 128 + col) = b;
        }
    }
    __syncthreads();

    // ---- epilogue pass 2: Vb = V + bf (ct 8..15 = waves 2,3), f32 ----
    if (wv >= 2) {
        #pragma unroll
        for (int tt = 0; tt < 4; ++tt) {
            int cb = ((wv - 2) * 4 + tt) * 64 + (lane >> 4) * 16;
            #pragma unroll
            for (int ns = 0; ns < 4; ++ns) {
                int node = ns * 16 + (lane & 15);
                int ba = (node * 512 + cb) ^ ((node & 7) << 4);
                *(f32x4*)(smem + ba) = acc[tt][ns];
            }
        }
    }
    __syncthreads();
    #pragma unroll
    for (int r = 0; r < 8; ++r) {
        int fo = r * 4096 + t * 16;
        int row = fo >> 9;
        int col = (fo & 511) >> 2;
        if (n0 + row < N) {
            f32x4 v = *(const f32x4*)(smem + (fo ^ ((row & 7) << 4)));
            f32x4 bias = *(const f32x4*)(bf + col);
            v[0] += bias[0]; v[1] += bias[1]; v[2] += bias[2]; v[3] += bias[3];
            *(f32x4*)(Vb + (size_t)(n0 + row) * 128 + col) = v;
        }
    }
}

// ---------------- CSR build ----------------

// XCD-windowed histogram: window w = blockIdx&7 -> XCD w. Atomics into the
// counts slice for this window stay in ONE XCD's L2 (no cross-XCD churn).
__global__ __launch_bounds__(256) void k_hist(
    const int* __restrict__ tgt, int* __restrict__ counts,
    int E, int wsz, int nchunk)
{
    const int win  = blockIdx.x & 7;
    const int step = gridDim.x >> 3;
    for (int c = blockIdx.x >> 3; c < nchunk; c += step) {
        int e = c * 256 + threadIdx.x;
        if (e < E) {
            int tg = tgt[e];
            if (tg / wsz == win) atomicAdd(&counts[tg], 1);
        }
    }
}

__global__ __launch_bounds__(256) void k_scan1(
    const int* __restrict__ counts, int* __restrict__ incl,
    int* __restrict__ partials, int N)
{
    __shared__ int sh[256];
    int t = threadIdx.x;
    int i = blockIdx.x * 256 + t;
    int v = (i < N) ? counts[i] : 0;
    sh[t] = v;
    __syncthreads();
    #pragma unroll
    for (int off = 1; off < 256; off <<= 1) {
        int add = (t >= off) ? sh[t - off] : 0;
        __syncthreads();
        sh[t] += add;
        __syncthreads();
    }
    if (i < N) incl[i] = sh[t];
    if (t == 255) partials[blockIdx.x] = sh[255];
}

__global__ __launch_bounds__(256) void k_scan2(int* __restrict__ partials, int nb)
{
    __shared__ int sh[256];
    int t = threadIdx.x;
    int v = (t < nb) ? partials[t] : 0;
    sh[t] = v;
    __syncthreads();
    #pragma unroll
    for (int off = 1; off < 256; off <<= 1) {
        int add = (t >= off) ? sh[t - off] : 0;
        __syncthreads();
        sh[t] += add;
        __syncthreads();
    }
    if (t < nb) partials[t] = sh[t] - v;   // exclusive
}

__global__ __launch_bounds__(256) void k_scan3(
    const int* __restrict__ counts, const int* __restrict__ incl,
    const int* __restrict__ partials, int* __restrict__ offsets,
    int* __restrict__ cursor, int N)
{
    int i = blockIdx.x * 256 + threadIdx.x;
    if (i >= N) return;
    int off = incl[i] - counts[i] + partials[i >> 8];
    offsets[i] = off;
    cursor[i]  = off;
}

// XCD-windowed scatter: window w = blockIdx&7 -> XCD w (round-robin mapping).
__global__ __launch_bounds__(256) void k_scatter(
    const int* __restrict__ src, const int* __restrict__ tgt,
    int* __restrict__ cursor, int* __restrict__ srcs,
    int E, int wsz, int nchunk)
{
    const int win  = blockIdx.x & 7;
    const int step = gridDim.x >> 3;
    for (int c = blockIdx.x >> 3; c < nchunk; c += step) {
        int e = c * 256 + threadIdx.x;
        if (e < E) {
            int tg = tgt[e];
            if (tg / wsz == win) {
                int pos = atomicAdd(&cursor[tg], 1);
                srcs[pos] = src[e];
            }
        }
    }
}

// ---- node aggregation: 32 lanes/node, 8-edge-deep gather pipeline ----

__global__ __launch_bounds__(256) void k_node(
    const short* __restrict__ Ub, const float* __restrict__ Vb,
    const double* __restrict__ p, const double* __restrict__ q,
    const int* __restrict__ offsets, const int* __restrict__ counts,
    const int* __restrict__ srcs, float* __restrict__ out, int N)
{
    int idx  = blockIdx.x * 256 + threadIdx.x;
    int n    = idx >> 5;                 // 32 lanes per node
    int lane = threadIdx.x & 31;
    if (n >= N) return;

    float4 Vn = ((const float4*)(Vb + (size_t)n * 128))[lane];
    double qn = q[n];                    // includes bw
    int beg = offsets[n];
    int cnt = counts[n];

    float ax = 0.f, ay = 0.f, az = 0.f, aw = 0.f;
    double as0 = 0.0, as1 = 0.0;

    int i = 0;
    for (; i + 8 <= cnt; i += 8) {
        // one lane-parallel index load, broadcast via shfl (width 32)
        int sv = srcs[beg + i + (lane & 7)];
        int s0 = __shfl(sv, 0, 32), s1 = __shfl(sv, 1, 32);
        int s2 = __shfl(sv, 2, 32), s3 = __shfl(sv, 3, 32);
        int s4 = __shfl(sv, 4, 32), s5 = __shfl(sv, 5, 32);
        int s6 = __shfl(sv, 6, 32), s7 = __shfl(sv, 7, 32);

        bf16x4 u0 = *(const bf16x4*)(Ub + (size_t)s0 * 128 + lane * 4);
        bf16x4 u1 = *(const bf16x4*)(Ub + (size_t)s1 * 128 + lane * 4);
        bf16x4 u2 = *(const bf16x4*)(Ub + (size_t)s2 * 128 + lane * 4);
        bf16x4 u3 = *(const bf16x4*)(Ub + (size_t)s3 * 128 + lane * 4);
        bf16x4 u4 = *(const bf16x4*)(Ub + (size_t)s4 * 128 + lane * 4);
        bf16x4 u5 = *(const bf16x4*)(Ub + (size_t)s5 * 128 + lane * 4);
        bf16x4 u6 = *(const bf16x4*)(Ub + (size_t)s6 * 128 + lane * 4);
        bf16x4 u7 = *(const bf16x4*)(Ub + (size_t)s7 * 128 + lane * 4);
        double a0 = p[s0] + qn, a1 = p[s1] + qn, a2 = p[s2] + qn, a3 = p[s3] + qn;
        double a4 = p[s4] + qn, a5 = p[s5] + qn, a6 = p[s6] + qn, a7 = p[s7] + qn;
        float f0 = (float)a0, f1 = (float)a1, f2 = (float)a2, f3 = (float)a3;
        float f4 = (float)a4, f5 = (float)a5, f6 = (float)a6, f7 = (float)a7;

        ax += fmaxf(bf16s_to_f32(u0[0]) + Vn.x, 0.f) * f0;
        ay += fmaxf(bf16s_to_f32(u0[1]) + Vn.y, 0.f) * f0;
        az += fmaxf(bf16s_to_f32(u0[2]) + Vn.z, 0.f) * f0;
        aw += fmaxf(bf16s_to_f32(u0[3]) + Vn.w, 0.f) * f0;
        ax += fmaxf(bf16s_to_f32(u1[0]) + Vn.x, 0.f) * f1;
        ay += fmaxf(bf16s_to_f32(u1[1]) + Vn.y, 0.f) * f1;
        az += fmaxf(bf16s_to_f32(u1[2]) + Vn.z, 0.f) * f1;
        aw += fmaxf(bf16s_to_f32(u1[3]) + Vn.w, 0.f) * f1;
        ax += fmaxf(bf16s_to_f32(u2[0]) + Vn.x, 0.f) * f2;
        ay += fmaxf(bf16s_to_f32(u2[1]) + Vn.y, 0.f) * f2;
        az += fmaxf(bf16s_to_f32(u2[2]) + Vn.z, 0.f) * f2;
        aw += fmaxf(bf16s_to_f32(u2[3]) + Vn.w, 0.f) * f2;
        ax += fmaxf(bf16s_to_f32(u3[0]) + Vn.x, 0.f) * f3;
        ay += fmaxf(bf16s_to_f32(u3[1]) + Vn.y, 0.f) * f3;
        az += fmaxf(bf16s_to_f32(u3[2]) + Vn.z, 0.f) * f3;
        aw += fmaxf(bf16s_to_f32(u3[3]) + Vn.w, 0.f) * f3;
        ax += fmaxf(bf16s_to_f32(u4[0]) + Vn.x, 0.f) * f4;
        ay += fmaxf(bf16s_to_f32(u4[1]) + Vn.y, 0.f) * f4;
        az += fmaxf(bf16s_to_f32(u4[2]) + Vn.z, 0.f) * f4;
        aw += fmaxf(bf16s_to_f32(u4[3]) + Vn.w, 0.f) * f4;
        ax += fmaxf(bf16s_to_f32(u5[0]) + Vn.x, 0.f) * f5;
        ay += fmaxf(bf16s_to_f32(u5[1]) + Vn.y, 0.f) * f5;
        az += fmaxf(bf16s_to_f32(u5[2]) + Vn.z, 0.f) * f5;
        aw += fmaxf(bf16s_to_f32(u5[3]) + Vn.w, 0.f) * f5;
        ax += fmaxf(bf16s_to_f32(u6[0]) + Vn.x, 0.f) * f6;
        ay += fmaxf(bf16s_to_f32(u6[1]) + Vn.y, 0.f) * f6;
        az += fmaxf(bf16s_to_f32(u6[2]) + Vn.z, 0.f) * f6;
        aw += fmaxf(bf16s_to_f32(u6[3]) + Vn.w, 0.f) * f6;
        ax += fmaxf(bf16s_to_f32(u7[0]) + Vn.x, 0.f) * f7;
        ay += fmaxf(bf16s_to_f32(u7[1]) + Vn.y, 0.f) * f7;
        az += fmaxf(bf16s_to_f32(u7[2]) + Vn.z, 0.f) * f7;
        aw += fmaxf(bf16s_to_f32(u7[3]) + Vn.w, 0.f) * f7;

        as0 += (a0 + a1) + (a2 + a3);
        as1 += (a4 + a5) + (a6 + a7);
    }
    for (; i < cnt; ++i) {
        int s = srcs[beg + i];
        bf16x4 u = *(const bf16x4*)(Ub + (size_t)s * 128 + lane * 4);
        double a = p[s] + qn;
        float af = (float)a;
        ax += fmaxf(bf16s_to_f32(u[0]) + Vn.x, 0.f) * af;
        ay += fmaxf(bf16s_to_f32(u[1]) + Vn.y, 0.f) * af;
        az += fmaxf(bf16s_to_f32(u[2]) + Vn.z, 0.f) * af;
        aw += fmaxf(bf16s_to_f32(u[3]) + Vn.w, 0.f) * af;
        as0 += a;
    }

    double inv = 1.0 / ((as0 + as1) + 1e-6);
    float4 o;
    o.x = (float)((double)ax * inv);
    o.y = (float)((double)ay * inv);
    o.z = (float)((double)az * inv);
    o.w = (float)((double)aw * inv);
    ((float4*)(out + (size_t)n * 128))[lane] = o;
}

extern "C" void kernel_launch(void* const* d_in, const int* in_sizes, int n_in,
                              void* d_out, int out_size, void* d_ws, size_t ws_size,
                              hipStream_t stream)
{
    const float* x   = (const float*)d_in[0];
    const float* Wf  = (const float*)d_in[1];
    const float* bf  = (const float*)d_in[2];
    const float* Ww  = (const float*)d_in[3];
    const float* bw  = (const float*)d_in[4];
    const int*   src = (const int*)d_in[5];
    const int*   tgt = (const int*)d_in[6];

    const int N = in_sizes[0] / 128;
    const int E = in_sizes[5];
    float* out = (float*)d_out;

    // workspace layout
    char* w = (char*)d_ws;
    short*  Ub       = (short*)w;                 w += (size_t)N * 128 * sizeof(short);
    float*  Vb       = (float*)w;                 w += (size_t)N * 128 * sizeof(float);
    double* p        = (double*)w;                w += (size_t)N * sizeof(double);
    double* q        = (double*)w;                w += (size_t)N * sizeof(double);
    int*    counts   = (int*)w;                   w += (size_t)N * sizeof(int);
    int*    incl     = (int*)w;                   w += (size_t)N * sizeof(int);
    int*    offsets  = (int*)w;                   w += (size_t)N * sizeof(int);
    int*    cursor   = (int*)w;                   w += (size_t)N * sizeof(int);
    int*    partials = (int*)w;                   w += 4096;
    int*    srcs     = (int*)w;                   w += (size_t)E * sizeof(int);
    short*  whp      = (short*)w;                 w += 256 * 128 * sizeof(short);
    short*  wlp      = (short*)w;

    hipMemsetAsync(counts, 0, (size_t)N * sizeof(int), stream);

    k_wconv<<<16, 256, 0, stream>>>(Wf, whp, wlp);
    k_transform<<<(N + 63) / 64, 256, 0, stream>>>(
        x, whp, wlp, bf, Ww, bw, Ub, Vb, p, q, N);

    int ebk = (E + 255) / 256;
    int nbk = (N + 255) / 256;
    int wsz = (N + 7) / 8;
    k_hist<<<4096, 256, 0, stream>>>(tgt, counts, E, wsz, ebk);
    k_scan1<<<nbk, 256, 0, stream>>>(counts, incl, partials, N);
    k_scan2<<<1, 256, 0, stream>>>(partials, nbk);
    k_scan3<<<nbk, 256, 0, stream>>>(counts, incl, partials, offsets, cursor, N);
    k_scatter<<<4096, 256, 0, stream>>>(src, tgt, cursor, srcs, E, wsz, ebk);

    long long nthreads = (long long)N * 32;
    k_node<<<(int)((nthreads + 255) / 256), 256, 0, stream>>>(
        Ub, Vb, p, q, offsets, counts, srcs, out, N);
}